// Round 7
// baseline (277.416 us; speedup 1.0000x reference)
//
#include <hip/hip_runtime.h>
#include <stdint.h>

// VQ codebook argmin. N=2048 queries (C=64) vs K=81920 codes.
// out (f32): [quantized_st 131072][vq_loss][commit_loss][idx 2048]
//
// Structure: bf16 pre-convert + bf16-MFMA prefilter (2 passes) + exact rescore.
//  conv : z,emb fp32 -> bf16 (rne) into ws
//  pass1: dot_bf(n,k) via mfma_f32_16x16x32_bf16, per-query global max
//  pass2: bit-identical MFMA, collect k with dot_bf >= max - DMARG
//  pass3: exact bitwise-numpy rescore, one WAVE per query; full-scan
//         fallback if candidate list overflowed (statistically never).
// Margin: numpy winner satisfies dot_bf(k*) >= max_bf - (3.9e-6 + 2*eps),
// eps <= 2^-8*||z||*||e|| <= 4.2e-6 => bound 1.23e-5; DMARG=1.6e-5.
// CAP=64 => overflow prob ~1e-14 per query, plus exact-scan fallback.
//
// R7 change: XCD-locality swizzle. 1D grid, xcd = bid&7; each XCD owns 20
// contiguous code-slices (1.28 MB ebf, L2-resident) shared by all 16
// q-blocks on that XCD -> ebf HBM-fetched once per pass (was 4x: round-6
// FETCH=41 MB/pass at 420-640 GB/s WAS the kernel duration).
#define NQ 2048
#define KK 81920
#define CD 64
#define CAP 64
#define DMARG 1.6e-5f
#define QPB 128              // queries per q-block (8 groups of 16)
#define NSLICE 160           // code slices of 512
#define NQBLK  16            // query blocks
#define SPX (NSLICE / 8)     // slices per XCD = 20

#define OUT_VQ 131072
#define OUT_CM 131073
#define OUT_IDX 131074

// ws layout (bytes)
#define WS_QMAX 0            // u32[2048]  f2o(max bf16 dot)  (memset 0)
#define WS_CNT  8192         // int[2048]  candidate counts   (memset 0)
#define WS_KEYS 16384        // u64[2048]  packed (score<<32|k)
#define WS_LOSS 32768        // float      loss accumulator
#define WS_CAND 33024        // int[2048*CAP]  (524288 B)
#define WS_ZBF  589824       // ushort[131072]   bf16 z      (262144 B)
#define WS_EBF  851968       // ushort[5242880]  bf16 emb    (10485760 B)

typedef short v8s __attribute__((ext_vector_type(8)));
typedef float v4f __attribute__((ext_vector_type(4)));

__device__ __forceinline__ unsigned int f2o(float f) {
  unsigned int u = __float_as_uint(f);
  return (u & 0x80000000u) ? ~u : (u | 0x80000000u);
}
__device__ __forceinline__ float o2f(unsigned int u) {
  unsigned int v = (u & 0x80000000u) ? (u & 0x7FFFFFFFu) : ~u;
  return __uint_as_float(v);
}
__device__ __forceinline__ unsigned int bf16rne(float f) {
  unsigned int u = __float_as_uint(f);
  u = u + 0x7FFFu + ((u >> 16) & 1u);
  return u >> 16;
}

// fp32 -> bf16 for z (32768 float4s) then emb (1310720 float4s), grid-stride.
#define NZ4 32768
#define NTOT4 1343488
__global__ __launch_bounds__(256) void convert_kernel(
    const float* __restrict__ z, const float* __restrict__ emb,
    unsigned int* __restrict__ zbf, unsigned int* __restrict__ ebf) {
  const int stride = gridDim.x * 256;
#pragma unroll 1
  for (int i = blockIdx.x * 256 + threadIdx.x; i < NTOT4; i += stride) {
    const bool isz = (i < NZ4);
    const float4 v = isz ? ((const float4*)z)[i] : ((const float4*)emb)[i - NZ4];
    uint2 o;
    o.x = bf16rne(v.x) | (bf16rne(v.y) << 16);
    o.y = bf16rne(v.z) | (bf16rne(v.w) << 16);
    if (isz) ((uint2*)zbf)[i] = o;
    else     ((uint2*)ebf)[i - NZ4] = o;
  }
}

// mfma_f32_16x16x32_bf16 layouts (m89/m91/m120):
//   A: lane holds A[m=lane&15][k=quad*8+j]
//   B: lane holds B[k=quad*8+j][n=lane&15]
//   D: lane,reg r -> D[row=quad*4+r][col=lane&15]   (row=query, col=code)
// Wave w owns codes [slice*512 + w*128, +128) -> 16 resident B-frags;
// loops 8 query-groups of 16 within its q-block.
template <bool COLLECT>
__global__ __launch_bounds__(256) void prefilter_kernel(
    const unsigned short* __restrict__ zbf, const unsigned short* __restrict__ ebf,
    unsigned int* __restrict__ qmax, int* __restrict__ cnt,
    int* __restrict__ cand) {
  const int tid = threadIdx.x;
  const int wave = tid >> 6, lane = tid & 63;
  const int quad = lane >> 4, lrow = lane & 15;
  // XCD-locality swizzle: bid&7 = XCD (empirical round-robin); each XCD gets
  // 20 contiguous slices shared by all its 16 q-blocks -> L2-resident ebf.
  const int bid = blockIdx.x;
  const int xcd = bid & 7;
  const int i = bid >> 3;                   // 0..319
  const int slice = xcd * SPX + (i % SPX);  // 0..159
  const int qblk = i / SPX;                 // 0..15
  const int code0 = slice * 512 + wave * 128;
  const int q0 = qblk * QPB;

  // B frags: 8 code-groups x 2 k-halves, one dwordx4 each
  v8s B[8][2];
#pragma unroll
  for (int cg = 0; cg < 8; ++cg) {
    const unsigned short* er = ebf + (size_t)(code0 + cg * 16 + lrow) * CD + quad * 8;
    B[cg][0] = *(const v8s*)er;
    B[cg][1] = *(const v8s*)(er + 32);
  }

#pragma unroll 1
  for (int qg = 0; qg < QPB / 16; ++qg) {
    const unsigned short* zr = zbf + (size_t)(q0 + qg * 16 + lrow) * CD + quad * 8;
    const v8s A0 = *(const v8s*)zr;
    const v8s A1 = *(const v8s*)(zr + 32);

    if (!COLLECT) {
      float pmax[4] = {-1e30f, -1e30f, -1e30f, -1e30f};
#pragma unroll
      for (int cg = 0; cg < 8; ++cg) {
        v4f acc = {0.f, 0.f, 0.f, 0.f};
        acc = __builtin_amdgcn_mfma_f32_16x16x32_bf16(A0, B[cg][0], acc, 0, 0, 0);
        acc = __builtin_amdgcn_mfma_f32_16x16x32_bf16(A1, B[cg][1], acc, 0, 0, 0);
#pragma unroll
        for (int r = 0; r < 4; ++r) pmax[r] = fmaxf(pmax[r], acc[r]);
      }
      // reduce over the 16 lanes (codes) in this quad's lane-group
#pragma unroll
      for (int m = 1; m <= 8; m <<= 1)
#pragma unroll
        for (int r = 0; r < 4; ++r)
          pmax[r] = fmaxf(pmax[r], __shfl_xor(pmax[r], m, 64));
      if (lrow == 0) {
#pragma unroll
        for (int r = 0; r < 4; ++r)
          atomicMax(&qmax[q0 + qg * 16 + quad * 4 + r], f2o(pmax[r]));
      }
    } else {
      const uint4 tv = *(const uint4*)(qmax + q0 + qg * 16 + quad * 4);
      float thr[4];
      thr[0] = o2f(tv.x) - DMARG; thr[1] = o2f(tv.y) - DMARG;
      thr[2] = o2f(tv.z) - DMARG; thr[3] = o2f(tv.w) - DMARG;
#pragma unroll
      for (int cg = 0; cg < 8; ++cg) {
        v4f acc = {0.f, 0.f, 0.f, 0.f};
        acc = __builtin_amdgcn_mfma_f32_16x16x32_bf16(A0, B[cg][0], acc, 0, 0, 0);
        acc = __builtin_amdgcn_mfma_f32_16x16x32_bf16(A1, B[cg][1], acc, 0, 0, 0);
        const float m01 = fmaxf(acc[0] - thr[0], acc[1] - thr[1]);
        const float m23 = fmaxf(acc[2] - thr[2], acc[3] - thr[3]);
        if (fmaxf(m01, m23) >= 0.0f) {  // rare
          const int code = code0 + cg * 16 + lrow;
#pragma unroll
          for (int r = 0; r < 4; ++r) {
            if (acc[r] >= thr[r]) {
              const int q = q0 + qg * 16 + quad * 4 + r;
              const int pos = atomicAdd(&cnt[q], 1);
              if (pos < CAP) cand[q * CAP + pos] = code;
            }
          }
        }
      }
    }
  }
}

// Exact bitwise-numpy score of code k (round-2/3 verified DAG).
__device__ __forceinline__ unsigned long long exact_key(
    const float* __restrict__ emb, const float zr[CD], float zn2, int k) {
#pragma clang fp contract(off)
  float er[CD];
  const float4* ep = (const float4*)(emb + (size_t)k * CD);
#pragma unroll
  for (int j = 0; j < 16; ++j) {
    float4 v = ep[j];
    er[4 * j] = v.x; er[4 * j + 1] = v.y; er[4 * j + 2] = v.z; er[4 * j + 3] = v.w;
  }
  float acc[16];
#pragma unroll
  for (int j = 0; j < 16; ++j) acc[j] = 0.0f;
#pragma unroll
  for (int q4 = 0; q4 < 16; ++q4) {
    const int jb = 4 * (q4 & 3), cb = 4 * q4;
    acc[jb + 0] = __builtin_fmaf(er[cb + 0], zr[cb + 0], acc[jb + 0]);
    acc[jb + 1] = __builtin_fmaf(er[cb + 1], zr[cb + 1], acc[jb + 1]);
    acc[jb + 2] = __builtin_fmaf(er[cb + 2], zr[cb + 2], acc[jb + 2]);
    acc[jb + 3] = __builtin_fmaf(er[cb + 3], zr[cb + 3], acc[jb + 3]);
  }
  float b8[8], b4[4];
#pragma unroll
  for (int j = 0; j < 8; ++j) b8[j] = acc[j] + acc[j + 8];
#pragma unroll
  for (int j = 0; j < 4; ++j) b4[j] = b8[j] + b8[j + 4];
  const float dot = (b4[0] + b4[2]) + (b4[1] + b4[3]);
  const float t = zn2 - 2.0f * dot;  // single rounding == numpy A - 2B
  return ((unsigned long long)f2o(t) << 32) | (unsigned int)k;
}

// One WAVE per query: lane l rescores candidate slot l; u64 lexicographic
// shuffle-min. Overflow (cnt > CAP) -> exact full scan by this wave.
__global__ __launch_bounds__(256) void rescore_kernel(
    const float* __restrict__ z, const float* __restrict__ emb,
    const int* __restrict__ cnt, const int* __restrict__ cand,
    unsigned long long* __restrict__ keys) {
#pragma clang fp contract(off)
  const int t = threadIdx.x;
  const int wv = t >> 6, lane = t & 63;
  const int n = blockIdx.x * 4 + wv;

  float zr[CD];
  {
    const float4* zp = (const float4*)(z + (size_t)n * CD);
#pragma unroll
    for (int i = 0; i < 16; ++i) {
      float4 v = zp[i];
      zr[4 * i] = v.x; zr[4 * i + 1] = v.y; zr[4 * i + 2] = v.z; zr[4 * i + 3] = v.w;
    }
  }
  float zn2;
  {
    float r[8];
#pragma unroll
    for (int j = 0; j < 8; ++j) r[j] = zr[j] * zr[j];
#pragma unroll
    for (int i = 8; i < CD; i += 8)
#pragma unroll
      for (int j = 0; j < 8; ++j) r[j] += zr[i + j] * zr[i + j];
    zn2 = ((r[0] + r[1]) + (r[2] + r[3])) + ((r[4] + r[5]) + (r[6] + r[7]));
  }

  const int c = cnt[n];
  unsigned long long best = ~0ull;
  if (c <= CAP) {
    if (lane < c) best = exact_key(emb, zr, zn2, cand[n * CAP + lane]);
  } else {
#pragma unroll 1
    for (int k = lane; k < KK; k += 64) {
      unsigned long long key = exact_key(emb, zr, zn2, k);
      best = (key < best) ? key : best;
    }
  }
#pragma unroll
  for (int m = 32; m; m >>= 1) {
    unsigned long long o = __shfl_xor(best, m, 64);
    best = (o < best) ? o : best;
  }
  if (lane == 0) keys[n] = best;
}

// 4 queries per block: quantized_st = z + (q - z) with numpy's two f32
// roundings, idx as float, accumulate sum((z-q)^2).
__global__ __launch_bounds__(256) void finalize_kernel(
    const float* __restrict__ z, const float* __restrict__ emb,
    const unsigned long long* __restrict__ keys, float* __restrict__ out,
    float* __restrict__ loss) {
#pragma clang fp contract(off)
  const int t = threadIdx.x;
  const int q = blockIdx.x * 4 + (t >> 6);
  const int c = t & 63;
  const int idx = (int)(keys[q] & 0xFFFFFFFFull);
  const float e = emb[(size_t)idx * CD + c];
  const float zv = z[(size_t)q * CD + c];
  const float dst = e - zv;
  out[(size_t)q * CD + c] = zv + dst;
  if (c == 0) out[OUT_IDX + q] = (float)idx;
  float d = zv - e;
  float sq = d * d;
#pragma unroll
  for (int off = 32; off > 0; off >>= 1) sq += __shfl_down(sq, off, 64);
  __shared__ float part[4];
  if (c == 0) part[t >> 6] = sq;
  __syncthreads();
  if (t == 0) atomicAdd(loss, part[0] + part[1] + part[2] + part[3]);
}

__global__ void write_losses(const float* __restrict__ loss, float* __restrict__ out) {
  float m = *loss / (float)(NQ * CD);
  out[OUT_VQ] = m;
  out[OUT_CM] = m;
}

extern "C" void kernel_launch(void* const* d_in, const int* in_sizes, int n_in,
                              void* d_out, int out_size, void* d_ws, size_t ws_size,
                              hipStream_t stream) {
  const float* z = (const float*)d_in[0];
  const float* emb = (const float*)d_in[1];
  float* out = (float*)d_out;
  char* ws = (char*)d_ws;
  unsigned int* qmax = (unsigned int*)(ws + WS_QMAX);
  int* cnt = (int*)(ws + WS_CNT);
  unsigned long long* keys = (unsigned long long*)(ws + WS_KEYS);
  float* loss = (float*)(ws + WS_LOSS);
  int* cand = (int*)(ws + WS_CAND);
  unsigned int* zbf = (unsigned int*)(ws + WS_ZBF);
  unsigned int* ebf = (unsigned int*)(ws + WS_EBF);

  hipMemsetAsync(qmax, 0, 2 * NQ * sizeof(int), stream);  // qmax + cnt
  hipMemsetAsync(loss, 0, sizeof(float), stream);

  convert_kernel<<<1312, 256, 0, stream>>>(z, emb, zbf, ebf);
  const int nblk = NSLICE * NQBLK;  // 2560, 1D with XCD swizzle
  prefilter_kernel<false><<<nblk, 256, 0, stream>>>(
      (const unsigned short*)zbf, (const unsigned short*)ebf, qmax, cnt, cand);
  prefilter_kernel<true><<<nblk, 256, 0, stream>>>(
      (const unsigned short*)zbf, (const unsigned short*)ebf, qmax, cnt, cand);
  rescore_kernel<<<NQ / 4, 256, 0, stream>>>(z, emb, cnt, cand, keys);
  finalize_kernel<<<NQ / 4, 256, 0, stream>>>(z, emb, keys, out, loss);
  write_losses<<<1, 1, 0, stream>>>(loss, out);
}

// Round 8
// 193.341 us; speedup vs baseline: 1.4349x; 1.4349x over previous
//
#include <hip/hip_runtime.h>
#include <stdint.h>

// VQ codebook argmin. N=2048 queries (C=64) vs K=81920 codes.
// out (f32): [quantized_st 131072][vq_loss][commit_loss][idx 2048]
//
// Structure: bf16 pre-convert + MFMA pass1 (per-slice max, atomic-free) +
// qmax reduce + MFMA collect pass + exact bitwise-numpy rescore.
// Margin: numpy winner satisfies dot_bf(k*) >= max_bf - (3.9e-6 + 2*eps),
// eps <= 2^-8*||z||*||e|| <= 4.2e-6 => bound 1.23e-5; DMARG=1.6e-5.
// CAP=64 + exact full-scan fallback on overflow.
#define NQ 2048
#define KK 81920
#define CD 64
#define CAP 64
#define DMARG 1.6e-5f
#define QPB 128              // queries per q-block (8 groups of 16)
#define NSLICE 160           // code slices of 512
#define NQBLK  16            // query blocks
#define SPX (NSLICE / 8)     // slices per XCD = 20

#define OUT_VQ 131072
#define OUT_CM 131073
#define OUT_IDX 131074

// ws layout (bytes)
#define WS_QMAX 0            // u32[2048]  f2o(max bf16 dot)
#define WS_CNT  8192         // int[2048]  candidate counts   (memset 0)
#define WS_KEYS 16384        // u64[2048]  packed (score<<32|k)
#define WS_LOSS 32768        // float      loss accumulator
#define WS_CAND 33024        // int[2048*CAP]  (524288 B)
#define WS_ZBF  589824       // ushort[131072]   bf16 z      (262144 B)
#define WS_EBF  851968       // ushort[5242880]  bf16 emb    (10485760 B)
#define WS_SMAX 11337728     // u32[2048*160] per-(q,slice) max (1310720 B)

typedef short v8s __attribute__((ext_vector_type(8)));
typedef float v4f __attribute__((ext_vector_type(4)));

__device__ __forceinline__ unsigned int f2o(float f) {
  unsigned int u = __float_as_uint(f);
  return (u & 0x80000000u) ? ~u : (u | 0x80000000u);
}
__device__ __forceinline__ float o2f(unsigned int u) {
  unsigned int v = (u & 0x80000000u) ? (u & 0x7FFFFFFFu) : ~u;
  return __uint_as_float(v);
}
__device__ __forceinline__ unsigned int bf16rne(float f) {
  unsigned int u = __float_as_uint(f);
  u = u + 0x7FFFu + ((u >> 16) & 1u);
  return u >> 16;
}

// fp32 -> bf16 for z (32768 float4s) then emb (1310720 float4s), grid-stride.
#define NZ4 32768
#define NTOT4 1343488
__global__ __launch_bounds__(256) void convert_kernel(
    const float* __restrict__ z, const float* __restrict__ emb,
    unsigned int* __restrict__ zbf, unsigned int* __restrict__ ebf) {
  const int stride = gridDim.x * 256;
#pragma unroll 1
  for (int i = blockIdx.x * 256 + threadIdx.x; i < NTOT4; i += stride) {
    const bool isz = (i < NZ4);
    const float4 v = isz ? ((const float4*)z)[i] : ((const float4*)emb)[i - NZ4];
    uint2 o;
    o.x = bf16rne(v.x) | (bf16rne(v.y) << 16);
    o.y = bf16rne(v.z) | (bf16rne(v.w) << 16);
    if (isz) ((uint2*)zbf)[i] = o;
    else     ((uint2*)ebf)[i - NZ4] = o;
  }
}

// Shared block-decode for both MFMA passes.
// Swizzle: xcd = bid&7 (round-robin dispatch); within an XCD, qblk varies
// fastest -> co-resident blocks share one 64KB B-slice (L2 reuse) but write
// DIFFERENT queries (no output contention).
struct BlkMap { int code0, q0, slice; };
__device__ __forceinline__ BlkMap decode_block(int bid, int wave) {
  const int xcd = bid & 7;
  const int i = bid >> 3;                 // 0..319
  const int qblk = i & 15;                // fastest
  const int slice = xcd * SPX + (i >> 4); // 0..159
  BlkMap m;
  m.slice = slice;
  m.code0 = slice * 512 + wave * 128;
  m.q0 = qblk * QPB;
  return m;
}

// mfma_f32_16x16x32_bf16 layouts (m89/m91/m120):
//   A: lane holds A[m=lane&15][k=quad*8+j]
//   B: lane holds B[k=quad*8+j][n=lane&15]
//   D: lane,reg r -> D[row=quad*4+r][col=lane&15]   (row=query, col=code)
// Wave w owns codes [slice*512 + w*128, +128) -> 16 resident B-frags.
// Fully unrolled: 32 loads hoisted, 128 MFMAs back-to-back, reductions
// batched at the end (32 independent 4-level chains), NO global atomics.
__global__ __launch_bounds__(256) void pass1_kernel(
    const unsigned short* __restrict__ zbf, const unsigned short* __restrict__ ebf,
    unsigned int* __restrict__ slicemax) {
  const int tid = threadIdx.x;
  const int wave = tid >> 6, lane = tid & 63;
  const int quad = lane >> 4, lrow = lane & 15;
  const BlkMap bm = decode_block(blockIdx.x, wave);

  v8s B[8][2];
#pragma unroll
  for (int cg = 0; cg < 8; ++cg) {
    const unsigned short* er = ebf + (size_t)(bm.code0 + cg * 16 + lrow) * CD + quad * 8;
    B[cg][0] = *(const v8s*)er;
    B[cg][1] = *(const v8s*)(er + 32);
  }
  v8s A0[8], A1[8];
#pragma unroll
  for (int qg = 0; qg < 8; ++qg) {
    const unsigned short* zr = zbf + (size_t)(bm.q0 + qg * 16 + lrow) * CD + quad * 8;
    A0[qg] = *(const v8s*)zr;
    A1[qg] = *(const v8s*)(zr + 32);
  }

  float pmax[8][4];
#pragma unroll
  for (int qg = 0; qg < 8; ++qg) {
#pragma unroll
    for (int r = 0; r < 4; ++r) pmax[qg][r] = -1e30f;
#pragma unroll
    for (int cg = 0; cg < 8; ++cg) {
      v4f acc = {0.f, 0.f, 0.f, 0.f};
      acc = __builtin_amdgcn_mfma_f32_16x16x32_bf16(A0[qg], B[cg][0], acc, 0, 0, 0);
      acc = __builtin_amdgcn_mfma_f32_16x16x32_bf16(A1[qg], B[cg][1], acc, 0, 0, 0);
#pragma unroll
      for (int r = 0; r < 4; ++r) pmax[qg][r] = fmaxf(pmax[qg][r], acc[r]);
    }
  }
  // batched 16-lane max reduce: 32 independent chains per level
#pragma unroll
  for (int m = 1; m <= 8; m <<= 1)
#pragma unroll
    for (int qg = 0; qg < 8; ++qg)
#pragma unroll
      for (int r = 0; r < 4; ++r)
        pmax[qg][r] = fmaxf(pmax[qg][r], __shfl_xor(pmax[qg][r], m, 64));

  // combine 4 waves via LDS, then one coalesced-ish store per query
  __shared__ unsigned int smax[4][QPB];
  if (lrow == 0) {
#pragma unroll
    for (int qg = 0; qg < 8; ++qg) {
      uint4 v;
      v.x = f2o(pmax[qg][0]); v.y = f2o(pmax[qg][1]);
      v.z = f2o(pmax[qg][2]); v.w = f2o(pmax[qg][3]);
      *(uint4*)&smax[wave][qg * 16 + quad * 4] = v;
    }
  }
  __syncthreads();
  if (tid < QPB) {
    unsigned int m0 = smax[0][tid], m1 = smax[1][tid];
    unsigned int m2 = smax[2][tid], m3 = smax[3][tid];
    unsigned int m01 = m0 > m1 ? m0 : m1;
    unsigned int m23 = m2 > m3 ? m2 : m3;
    slicemax[(size_t)(bm.q0 + tid) * NSLICE + bm.slice] = m01 > m23 ? m01 : m23;
  }
}

// qmax[q] = max over 160 slice maxima (u32 order == score order).
__global__ __launch_bounds__(256) void reduce_qmax_kernel(
    const unsigned int* __restrict__ slicemax, unsigned int* __restrict__ qmax) {
  const int t = threadIdx.x, wv = t >> 6, lane = t & 63;
  const int q = blockIdx.x * 4 + wv;
  const unsigned int* row = slicemax + (size_t)q * NSLICE;
  unsigned int m = row[lane];
  unsigned int m2 = row[lane + 64];
  m = m > m2 ? m : m2;
  if (lane < 32) { unsigned int m3 = row[lane + 128]; m = m > m3 ? m : m3; }
#pragma unroll
  for (int s = 32; s; s >>= 1) {
    unsigned int o = (unsigned int)__shfl_xor((int)m, s, 64);
    m = m > o ? m : o;
  }
  if (lane == 0) qmax[q] = m;
}

// Collect pass: bit-identical MFMA chains; k with dot >= qmax - DMARG.
__global__ __launch_bounds__(256) void collect_kernel(
    const unsigned short* __restrict__ zbf, const unsigned short* __restrict__ ebf,
    const unsigned int* __restrict__ qmax, int* __restrict__ cnt,
    int* __restrict__ cand) {
  const int tid = threadIdx.x;
  const int wave = tid >> 6, lane = tid & 63;
  const int quad = lane >> 4, lrow = lane & 15;
  const BlkMap bm = decode_block(blockIdx.x, wave);

  v8s B[8][2];
#pragma unroll
  for (int cg = 0; cg < 8; ++cg) {
    const unsigned short* er = ebf + (size_t)(bm.code0 + cg * 16 + lrow) * CD + quad * 8;
    B[cg][0] = *(const v8s*)er;
    B[cg][1] = *(const v8s*)(er + 32);
  }
  v8s A0[8], A1[8];
#pragma unroll
  for (int qg = 0; qg < 8; ++qg) {
    const unsigned short* zr = zbf + (size_t)(bm.q0 + qg * 16 + lrow) * CD + quad * 8;
    A0[qg] = *(const v8s*)zr;
    A1[qg] = *(const v8s*)(zr + 32);
  }
  float thr[8][4];
#pragma unroll
  for (int qg = 0; qg < 8; ++qg) {
    const uint4 tv = *(const uint4*)(qmax + bm.q0 + qg * 16 + quad * 4);
    thr[qg][0] = o2f(tv.x) - DMARG; thr[qg][1] = o2f(tv.y) - DMARG;
    thr[qg][2] = o2f(tv.z) - DMARG; thr[qg][3] = o2f(tv.w) - DMARG;
  }

#pragma unroll
  for (int qg = 0; qg < 8; ++qg) {
#pragma unroll
    for (int cg = 0; cg < 8; ++cg) {
      v4f acc = {0.f, 0.f, 0.f, 0.f};
      acc = __builtin_amdgcn_mfma_f32_16x16x32_bf16(A0[qg], B[cg][0], acc, 0, 0, 0);
      acc = __builtin_amdgcn_mfma_f32_16x16x32_bf16(A1[qg], B[cg][1], acc, 0, 0, 0);
      const float m01 = fmaxf(acc[0] - thr[qg][0], acc[1] - thr[qg][1]);
      const float m23 = fmaxf(acc[2] - thr[qg][2], acc[3] - thr[qg][3]);
      if (fmaxf(m01, m23) >= 0.0f) {  // rare (~6 hits/query total)
        const int code = bm.code0 + cg * 16 + lrow;
#pragma unroll
        for (int r = 0; r < 4; ++r) {
          if (acc[r] >= thr[qg][r]) {
            const int q = bm.q0 + qg * 16 + quad * 4 + r;
            const int pos = atomicAdd(&cnt[q], 1);
            if (pos < CAP) cand[q * CAP + pos] = code;
          }
        }
      }
    }
  }
}

// Exact bitwise-numpy score of code k (round-2/3 verified DAG).
__device__ __forceinline__ unsigned long long exact_key(
    const float* __restrict__ emb, const float zr[CD], float zn2, int k) {
#pragma clang fp contract(off)
  float er[CD];
  const float4* ep = (const float4*)(emb + (size_t)k * CD);
#pragma unroll
  for (int j = 0; j < 16; ++j) {
    float4 v = ep[j];
    er[4 * j] = v.x; er[4 * j + 1] = v.y; er[4 * j + 2] = v.z; er[4 * j + 3] = v.w;
  }
  float acc[16];
#pragma unroll
  for (int j = 0; j < 16; ++j) acc[j] = 0.0f;
#pragma unroll
  for (int q4 = 0; q4 < 16; ++q4) {
    const int jb = 4 * (q4 & 3), cb = 4 * q4;
    acc[jb + 0] = __builtin_fmaf(er[cb + 0], zr[cb + 0], acc[jb + 0]);
    acc[jb + 1] = __builtin_fmaf(er[cb + 1], zr[cb + 1], acc[jb + 1]);
    acc[jb + 2] = __builtin_fmaf(er[cb + 2], zr[cb + 2], acc[jb + 2]);
    acc[jb + 3] = __builtin_fmaf(er[cb + 3], zr[cb + 3], acc[jb + 3]);
  }
  float b8[8], b4[4];
#pragma unroll
  for (int j = 0; j < 8; ++j) b8[j] = acc[j] + acc[j + 8];
#pragma unroll
  for (int j = 0; j < 4; ++j) b4[j] = b8[j] + b8[j + 4];
  const float dot = (b4[0] + b4[2]) + (b4[1] + b4[3]);
  const float t = zn2 - 2.0f * dot;  // single rounding == numpy A - 2B
  return ((unsigned long long)f2o(t) << 32) | (unsigned int)k;
}

// One WAVE per query: lane l rescores candidate slot l; u64 lexicographic
// shuffle-min. Overflow (cnt > CAP) -> exact full scan by this wave.
__global__ __launch_bounds__(256) void rescore_kernel(
    const float* __restrict__ z, const float* __restrict__ emb,
    const int* __restrict__ cnt, const int* __restrict__ cand,
    unsigned long long* __restrict__ keys) {
#pragma clang fp contract(off)
  const int t = threadIdx.x;
  const int wv = t >> 6, lane = t & 63;
  const int n = blockIdx.x * 4 + wv;

  float zr[CD];
  {
    const float4* zp = (const float4*)(z + (size_t)n * CD);
#pragma unroll
    for (int i = 0; i < 16; ++i) {
      float4 v = zp[i];
      zr[4 * i] = v.x; zr[4 * i + 1] = v.y; zr[4 * i + 2] = v.z; zr[4 * i + 3] = v.w;
    }
  }
  float zn2;
  {
    float r[8];
#pragma unroll
    for (int j = 0; j < 8; ++j) r[j] = zr[j] * zr[j];
#pragma unroll
    for (int i = 8; i < CD; i += 8)
#pragma unroll
      for (int j = 0; j < 8; ++j) r[j] += zr[i + j] * zr[i + j];
    zn2 = ((r[0] + r[1]) + (r[2] + r[3])) + ((r[4] + r[5]) + (r[6] + r[7]));
  }

  const int c = cnt[n];
  unsigned long long best = ~0ull;
  if (c <= CAP) {
    if (lane < c) best = exact_key(emb, zr, zn2, cand[n * CAP + lane]);
  } else {
#pragma unroll 1
    for (int k = lane; k < KK; k += 64) {
      unsigned long long key = exact_key(emb, zr, zn2, k);
      best = (key < best) ? key : best;
    }
  }
#pragma unroll
  for (int m = 32; m; m >>= 1) {
    unsigned long long o = __shfl_xor(best, m, 64);
    best = (o < best) ? o : best;
  }
  if (lane == 0) keys[n] = best;
}

// 4 queries per block: quantized_st = z + (q - z) with numpy's two f32
// roundings, idx as float, accumulate sum((z-q)^2).
__global__ __launch_bounds__(256) void finalize_kernel(
    const float* __restrict__ z, const float* __restrict__ emb,
    const unsigned long long* __restrict__ keys, float* __restrict__ out,
    float* __restrict__ loss) {
#pragma clang fp contract(off)
  const int t = threadIdx.x;
  const int q = blockIdx.x * 4 + (t >> 6);
  const int c = t & 63;
  const int idx = (int)(keys[q] & 0xFFFFFFFFull);
  const float e = emb[(size_t)idx * CD + c];
  const float zv = z[(size_t)q * CD + c];
  const float dst = e - zv;
  out[(size_t)q * CD + c] = zv + dst;
  if (c == 0) out[OUT_IDX + q] = (float)idx;
  float d = zv - e;
  float sq = d * d;
#pragma unroll
  for (int off = 32; off > 0; off >>= 1) sq += __shfl_down(sq, off, 64);
  __shared__ float part[4];
  if (c == 0) part[t >> 6] = sq;
  __syncthreads();
  if (t == 0) atomicAdd(loss, part[0] + part[1] + part[2] + part[3]);
}

__global__ void write_losses(const float* __restrict__ loss, float* __restrict__ out) {
  float m = *loss / (float)(NQ * CD);
  out[OUT_VQ] = m;
  out[OUT_CM] = m;
}

extern "C" void kernel_launch(void* const* d_in, const int* in_sizes, int n_in,
                              void* d_out, int out_size, void* d_ws, size_t ws_size,
                              hipStream_t stream) {
  const float* z = (const float*)d_in[0];
  const float* emb = (const float*)d_in[1];
  float* out = (float*)d_out;
  char* ws = (char*)d_ws;
  unsigned int* qmax = (unsigned int*)(ws + WS_QMAX);
  int* cnt = (int*)(ws + WS_CNT);
  unsigned long long* keys = (unsigned long long*)(ws + WS_KEYS);
  float* loss = (float*)(ws + WS_LOSS);
  int* cand = (int*)(ws + WS_CAND);
  unsigned int* zbf = (unsigned int*)(ws + WS_ZBF);
  unsigned int* ebf = (unsigned int*)(ws + WS_EBF);
  unsigned int* slicemax = (unsigned int*)(ws + WS_SMAX);

  hipMemsetAsync(cnt, 0, NQ * sizeof(int), stream);
  hipMemsetAsync(loss, 0, sizeof(float), stream);

  convert_kernel<<<1312, 256, 0, stream>>>(z, emb, zbf, ebf);
  const int nblk = NSLICE * NQBLK;  // 2560, 1D with XCD swizzle
  pass1_kernel<<<nblk, 256, 0, stream>>>(
      (const unsigned short*)zbf, (const unsigned short*)ebf, slicemax);
  reduce_qmax_kernel<<<NQ / 4, 256, 0, stream>>>(slicemax, qmax);
  collect_kernel<<<nblk, 256, 0, stream>>>(
      (const unsigned short*)zbf, (const unsigned short*)ebf, qmax, cnt, cand);
  rescore_kernel<<<NQ / 4, 256, 0, stream>>>(z, emb, cnt, cand, keys);
  finalize_kernel<<<NQ / 4, 256, 0, stream>>>(z, emb, keys, out, loss);
  write_losses<<<1, 1, 0, stream>>>(loss, out);
}